// Round 1
// baseline (2120.151 us; speedup 1.0000x reference)
//
#include <hip/hip_runtime.h>
#include <math.h>

#define H   39
#define G4  156   // 4*H
#define TL  2048  // T
#define BB  512   // B

__device__ __forceinline__ float sigmoid_f(float x) {
    // safe at extremes: x<<0 -> exp(+inf) -> 1/inf = 0 ; x>>0 -> exp(0-) -> 1
    return 1.0f / (1.0f + __expf(-x));
}

__device__ __forceinline__ float tanh_f(float x) {
    // tanh(|x|) = 1 - 2/(exp(2|x|)+1); safe when exp overflows to +inf (-> 1)
    float a = fabsf(x);
    float e = __expf(2.0f * a);
    float t = 1.0f - 2.0f / (e + 1.0f);
    return copysignf(t, x);
}

__global__ __launch_bounds__(192, 3)
void lstm_bidir_kernel(const float* __restrict__ x,
                       const float* __restrict__ W_ih_f, const float* __restrict__ W_hh_f,
                       const float* __restrict__ b_ih_f, const float* __restrict__ b_hh_f,
                       const float* __restrict__ W_ih_b, const float* __restrict__ W_hh_b,
                       const float* __restrict__ b_ih_b, const float* __restrict__ b_hh_b,
                       float* __restrict__ out)
{
    const int blk = blockIdx.x;        // 0..1023
    const int b   = blk >> 1;          // batch element
    const int dir = blk & 1;           // 0 = forward, 1 = backward
    const int j   = threadIdx.x;       // gate row when < 156

    const float* W_ih = dir ? W_ih_b : W_ih_f;
    const float* W_hh = dir ? W_hh_b : W_hh_f;
    const float* b_ih = dir ? b_ih_b : b_ih_f;
    const float* b_hh = dir ? b_hh_b : b_hh_f;

    __shared__ float h_buf[40];    // padded to 40 for aligned vector reads
    __shared__ float x_buf[40];
    __shared__ float gates[G4];

    // Per-thread weight rows in registers: 2*39 = 78 VGPRs, reused 2048 times.
    float wih[H], whh[H];
    float bias = 0.0f;
    if (j < G4) {
        #pragma unroll
        for (int k = 0; k < H; ++k) {
            wih[k] = W_ih[j * H + k];
            whh[k] = W_hh[j * H + k];
        }
        bias = b_ih[j] + b_hh[j];
    }

    // x layout: (B, T, H) flat. out layout: (B, T, 2H) flat.
    const float* xrow = x + (size_t)b * (TL * H);
    float* orow = out + (size_t)b * (TL * 2 * H) + dir * H;

    float c = 0.0f;                 // cell state, lives in threads j < H
    if (j < H) {
        h_buf[j] = 0.0f;
        const int t0 = dir ? (TL - 1) : 0;
        x_buf[j] = xrow[t0 * H + j];
    }
    __syncthreads();

    for (int s = 0; s < TL; ++s) {
        // Prefetch next timestep's x while the dot products run.
        float xnext = 0.0f;
        if (j < H && (s + 1) < TL) {
            const int tn = dir ? (TL - 2 - s) : (s + 1);
            xnext = xrow[tn * H + j];
        }

        if (j < G4) {
            float acc0 = bias, acc1 = 0.0f;
            #pragma unroll
            for (int k = 0; k < H; ++k) {
                acc0 = fmaf(wih[k], x_buf[k], acc0);  // input projection (fused)
                acc1 = fmaf(whh[k], h_buf[k], acc1);  // recurrent projection
            }
            const float g = acc0 + acc1;
            // gate order i, f, g, o : rows [0,39) [39,78) [78,117) [117,156)
            const float act = (j >= 2 * H && j < 3 * H) ? tanh_f(g) : sigmoid_f(g);
            gates[j] = act;
        }
        __syncthreads();   // gates ready; everyone done reading h_buf/x_buf

        if (j < H) {
            const float ig = gates[j];
            const float fg = gates[H + j];
            const float gg = gates[2 * H + j];
            const float og = gates[3 * H + j];
            c = fmaf(fg, c, ig * gg);
            const float h = og * tanh_f(c);
            h_buf[j] = h;
            x_buf[j] = xnext;
            orow[(size_t)s * (2 * H) + j] = h;   // bwd dir: h_b_rev[s] lands at time index s
        }
        __syncthreads();   // h_buf/x_buf updated before next step reads them
    }
}

extern "C" void kernel_launch(void* const* d_in, const int* in_sizes, int n_in,
                              void* d_out, int out_size, void* d_ws, size_t ws_size,
                              hipStream_t stream) {
    const float* x      = (const float*)d_in[0];
    const float* W_ih_f = (const float*)d_in[1];
    const float* W_hh_f = (const float*)d_in[2];
    const float* b_ih_f = (const float*)d_in[3];
    const float* b_hh_f = (const float*)d_in[4];
    const float* W_ih_b = (const float*)d_in[5];
    const float* W_hh_b = (const float*)d_in[6];
    const float* b_ih_b = (const float*)d_in[7];
    const float* b_hh_b = (const float*)d_in[8];
    float* out = (float*)d_out;

    dim3 grid(BB * 2);   // one block per (batch, direction)
    dim3 block(192);     // 3 waves; threads 0..155 own gate rows
    lstm_bidir_kernel<<<grid, block, 0, stream>>>(
        x, W_ih_f, W_hh_f, b_ih_f, b_hh_f,
        W_ih_b, W_hh_b, b_ih_b, b_hh_b, out);
}